// Round 15
// baseline (241.415 us; speedup 1.0000x reference)
//
#include <hip/hip_runtime.h>
#include <cmath>

#define B_ 2
#define S_ 2048
#define D_ 1024
#define H_ 16
#define HD_ 64
#define M_ 4096   // B*S

typedef __attribute__((ext_vector_type(8))) short short8;
typedef __attribute__((ext_vector_type(4))) short short4v;
typedef __attribute__((ext_vector_type(4))) float f32x4;

// round-to-nearest-even f32 -> bf16 (values finite here)
__device__ __forceinline__ short f2bf(float x) {
    unsigned u = __builtin_bit_cast(unsigned, x);
    u += 0x7fffu + ((u >> 16) & 1u);
    return (short)(u >> 16);
}

__device__ __forceinline__ void gload_lds16(const short* g, short* l) {
    __builtin_amdgcn_global_load_lds(
        (const __attribute__((address_space(1))) unsigned int*)g,
        (__attribute__((address_space(3))) unsigned int*)l, 16, 0, 0);
}

// counted vmcnt wait — prefetches stay in flight across barriers
template<int N> __device__ __forceinline__ void vwait() {
    if constexpr (N == 0) asm volatile("s_waitcnt vmcnt(0)" ::: "memory");
    else if constexpr (N == 2) asm volatile("s_waitcnt vmcnt(2)" ::: "memory");
    else if constexpr (N == 4) asm volatile("s_waitcnt vmcnt(4)" ::: "memory");
}
__device__ __forceinline__ void bar() { __builtin_amdgcn_s_barrier(); }

// ---------------------------------------------------------------------------
// cast fp32 inputs to bf16
__global__ __launch_bounds__(256) void cast_all_kernel(
    const float* __restrict__ x,  const float* __restrict__ Wq,
    const float* __restrict__ Wk, const float* __restrict__ Wv,
    const float* __restrict__ Wo,
    short* __restrict__ xb, short* __restrict__ Wqkvb, short* __restrict__ Wob)
{
    const size_t i = (size_t)blockIdx.x * 256 + threadIdx.x;  // float4 index
    const float* src; short* dst; size_t off;
    if (i < 1048576)      { src = x;  dst = xb;              off = i; }
    else if (i < 1310720) { src = Wq; dst = Wqkvb;           off = i - 1048576; }
    else if (i < 1572864) { src = Wk; dst = Wqkvb + 1048576; off = i - 1310720; }
    else if (i < 1835008) { src = Wv; dst = Wqkvb + 2097152; off = i - 1572864; }
    else                  { src = Wo; dst = Wob;             off = i - 1835008; }
    float4 v = ((const float4*)src)[off];
    short4v o = { f2bf(v.x), f2bf(v.y), f2bf(v.z), f2bf(v.w) };
    ((short4v*)dst)[off] = o;
}

// ---------------------------------------------------------------------------
// QKV GEMM — 2-phase 256x256 template (catalog m230/m248: 655-682 TF at
// K=1024, refcheck'd). The 128^2/4-wave family pinned at ~290 TF across six
// schedules because each barrier period holds only 16 MFMA/wave; this tile
// gives 64 MFMA/wave/period (4x compute behind each sync) with the SAME
// proven pieces. BK=64, 8 waves (2Mx4N), wave tile 128x64, acc 8x4.
// Per K-tile: STAGE(next tile -> other buffer; 8 gloads/thread) ->
// COMP(cur; 24 ds_read_b128 + 64 MFMA/wave) -> vmcnt(0) -> s_barrier.
// The drain is covered by the full compute phase (~1000+ cy); buffer reuse
// is fenced by the barrier after the COMP that last read it.
// LDS 4 x 32 KB = 128 KB -> 1 block/CU; grid 192 = 16mr x 12nc with
// bijective XCD-contiguous remap. LDS rows 64 shorts (128B); 16B slot s of
// row r holds data slot s^(r&7) (pre-swizzled global source, linear LDS
// dest; same XOR on b128 reads -> conflict-free, verified all session).
// Fused epilogue: q,k bias+RoPE -> [BH,S,HD]; v bias -> [BH,HD,S].
// n-tiles are 256-wide at 256-aligned offsets -> never straddle q/k/v.
__global__ __launch_bounds__(512, 2) void gemm_qkv256(
    const short* __restrict__ A, const short* __restrict__ Bw,
    const float* __restrict__ b0p, const float* __restrict__ b1p, const float* __restrict__ b2p,
    const float* __restrict__ freqs,
    short* __restrict__ out0, short* __restrict__ out1, short* __restrict__ out2)
{
    __shared__ __align__(16) short A0[256*64];
    __shared__ __align__(16) short A1[256*64];
    __shared__ __align__(16) short B0[256*64];
    __shared__ __align__(16) short B1[256*64];
    const int t = threadIdx.x;
    const int w = t >> 6;                       // 0..7
    const int lane = t & 63;
    const int qd = lane >> 4, l = lane & 15;
    const int l7 = lane & 7;
    // bijective XCD-contiguous remap on 192 = 8 x 24 = 16mr x 12nc
    const int bid = blockIdx.x;
    const int xcd = bid & 7, idx = bid >> 3;    // idx 0..23
    const int mr = xcd * 2 + idx / 12;          // 0..15
    const int nc = idx % 12;                    // 0..11
    const int m0 = mr * 256, n0 = nc * 256;
    const int wr = (w >> 2) * 128;              // 0 / 128
    const int wc = (w & 3) * 64;                // 0..192
    // staging: one gload call = 64 rows x 128B across the block; wave w
    // covers 8 rows; lane -> (row rl, pre-swizzled source slot ss8)
    const int rl  = lane >> 3;                  // 0..7
    const int ss8 = ((lane & 7) ^ rl) << 3;

    f32x4 acc[8][4] = {};

    auto STAGE = [&](int c, short* As, short* Bss) {
        const int k0 = c * 64;
        #pragma unroll
        for (int j = 0; j < 4; ++j) {
            const int r0 = j*64 + w*8;
            gload_lds16(A + (size_t)(m0 + r0 + rl)*1024 + k0 + ss8, &As[r0*64]);
        }
        #pragma unroll
        for (int j = 0; j < 4; ++j) {
            const int r0 = j*64 + w*8;
            gload_lds16(Bw + (size_t)(n0 + r0 + rl)*1024 + k0 + ss8, &Bss[r0*64]);
        }
    };

    auto COMP = [&](const short* As, const short* Bss) {
        #pragma unroll
        for (int kk = 0; kk < 2; ++kk) {
            short8 af[8], bfr[4];
            #pragma unroll
            for (int rt = 0; rt < 8; ++rt)
                af[rt] = *(const short8*)&As[(wr + rt*16 + l)*64 + (((kk*4 + qd) ^ l7) << 3)];
            #pragma unroll
            for (int ct = 0; ct < 4; ++ct)
                bfr[ct] = *(const short8*)&Bss[(wc + ct*16 + l)*64 + (((kk*4 + qd) ^ l7) << 3)];
            #pragma unroll
            for (int rt = 0; rt < 8; ++rt)
                #pragma unroll
                for (int ct = 0; ct < 4; ++ct)
                    acc[rt][ct] = __builtin_amdgcn_mfma_f32_16x16x32_bf16(af[rt], bfr[ct], acc[rt][ct], 0, 0, 0);
        }
    };

    // 16 K-tiles of BK=64, 2-phase: stage next before compute, one
    // vmcnt(0)+barrier per tile. Pair-unrolled static dbuf.
    STAGE(0, A0, B0);
    vwait<0>(); bar();
    for (int p = 0; p < 16; p += 2) {
        STAGE(p + 1, A1, B1);           // loads fly over COMP below
        COMP(A0, B0);
        vwait<0>(); bar();              // tile p+1 landed; A0/B0 free
        if (p + 2 < 16)
            STAGE(p + 2, A0, B0);
        COMP(A1, B1);
        vwait<0>(); bar();
    }

    // fused QKV epilogue
    const int sel = n0 >> 10;          // 0=q 1=k 2=v (uniform per block)
    const int nb = n0 & 1023;
    const float* bias = (sel == 0) ? b0p : (sel == 1) ? b1p : b2p;
    if (sel < 2) {
        short* outg = (sel == 0) ? out0 : out1;
        #pragma unroll
        for (int rt = 0; rt < 8; ++rt)
            #pragma unroll
            for (int ct = 0; ct < 4; ++ct) {
                const int d = nb + wc + ct*16 + l;
                const float bsv = bias[d];
                const int h = d >> 6, hd = d & 63;
                #pragma unroll
                for (int r = 0; r < 4; ++r) {
                    const int m = m0 + wr + rt*16 + qd*4 + r;
                    const int bb = m >> 11, s = m & 2047;
                    float val = acc[rt][ct][r] + bsv;
                    float pv = __shfl_xor(val, 1);
                    const float* f = freqs + (size_t)s*128 + (size_t)(hd >> 1)*4;
                    float o = (d & 1) ? (f[2]*pv + f[3]*val) : (f[0]*val + f[1]*pv);
                    outg[((size_t)(bb*16 + h)*2048 + s)*64 + hd] = f2bf(o);
                }
            }
    } else {
        #pragma unroll
        for (int rt = 0; rt < 8; ++rt)
            #pragma unroll
            for (int ct = 0; ct < 4; ++ct) {
                const int d = nb + wc + ct*16 + l;
                const float bsv = bias[d];
                const int h = d >> 6, hd = d & 63;
                const int m0r = m0 + wr + rt*16 + qd*4;
                const int bb = m0r >> 11, s0 = m0r & 2047;
                short4v pk;
                #pragma unroll
                for (int r = 0; r < 4; ++r) pk[r] = f2bf(acc[rt][ct][r] + bsv);
                *(short4v*)&out2[((size_t)(bb*16 + h)*64 + hd)*2048 + s0] = pk;  // v^T
            }
    }
}

// ---------------------------------------------------------------------------
// proj GEMM — BK=64, 64x64 tile, sa2 counted stage-ahead-2 + XCD remap
// (R14 verbatim). 3 static buffers, 48 KB LDS -> 3 blocks/CU, grid 1024.
// LDS rows 64 shorts (128B); data slot s of row r at LDS slot s^(r&7).
__global__ __launch_bounds__(256) void gemm_proj64(
    const short* __restrict__ A, const short* __restrict__ Bw,
    const float* __restrict__ b0p, float* __restrict__ out)
{
    __shared__ __align__(16) short A0[64*64];
    __shared__ __align__(16) short A1[64*64];
    __shared__ __align__(16) short A2[64*64];
    __shared__ __align__(16) short B0[64*64];
    __shared__ __align__(16) short B1[64*64];
    __shared__ __align__(16) short B2[64*64];
    const int t = threadIdx.x;
    const int w = t >> 6;
    const int lane = t & 63;
    const int qd = lane >> 4, l = lane & 15;
    const int l7 = lane & 7;
    const int bid = blockIdx.x;
    const int xcd = bid & 7, idx = bid >> 3;   // idx 0..127
    const int mr = xcd * 8 + (idx >> 4);       // 0..63
    const int nc = idx & 15;                   // 0..15
    const int n0 = nc * 64, m0 = mr * 64;
    const int wr = (w >> 1) * 32, wc = (w & 1) * 32;
    const int rl  = lane >> 3;
    const int ss8 = ((lane & 7) ^ rl) << 3;    // pre-swizzled source slot

    f32x4 acc[2][2] = {};

    auto STAGE = [&](int c, short* As, short* Bss) {
        const int k0 = c * 64;
        #pragma unroll
        for (int j = 0; j < 2; ++j) {
            const int r0 = (j*4 + w) * 8;
            gload_lds16(A  + (size_t)(m0 + r0 + rl)*1024 + k0 + ss8, &As[r0*64]);
            gload_lds16(Bw + (size_t)(n0 + r0 + rl)*1024 + k0 + ss8, &Bss[r0*64]);
        }
    };

    auto COMP = [&](const short* As, const short* Bss) {
        #pragma unroll
        for (int kk = 0; kk < 2; ++kk) {
            short8 af[2], bfr[2];
            #pragma unroll
            for (int rt = 0; rt < 2; ++rt)
                af[rt] = *(const short8*)&As[(wr + rt*16 + l)*64 + (((kk*4 + qd) ^ l7) << 3)];
            #pragma unroll
            for (int ct = 0; ct < 2; ++ct)
                bfr[ct] = *(const short8*)&Bss[(wc + ct*16 + l)*64 + (((kk*4 + qd) ^ l7) << 3)];
            #pragma unroll
            for (int rt = 0; rt < 2; ++rt)
                #pragma unroll
                for (int ct = 0; ct < 2; ++ct)
                    acc[rt][ct] = __builtin_amdgcn_mfma_f32_16x16x32_bf16(af[rt], bfr[ct], acc[rt][ct], 0, 0, 0);
        }
    };

    STAGE(0, A0, B0);
    STAGE(1, A1, B1);
    for (int p = 0; p <= 9; p += 3) {       // computes 0..11, stages 2..13
        vwait<4>(); bar();
        STAGE(p + 2, A2, B2);
        COMP(A0, B0);
        vwait<4>(); bar();
        STAGE(p + 3, A0, B0);
        COMP(A1, B1);
        vwait<4>(); bar();
        STAGE(p + 4, A1, B1);
        COMP(A2, B2);
    }
    vwait<4>(); bar();
    STAGE(14, A2, B2);
    COMP(A0, B0);                           // chunk 12
    vwait<4>(); bar();
    STAGE(15, A0, B0);
    COMP(A1, B1);                           // chunk 13
    vwait<4>(); bar();
    COMP(A2, B2);                           // chunk 14
    vwait<0>(); bar();
    COMP(A0, B0);                           // chunk 15

    #pragma unroll
    for (int rt = 0; rt < 2; ++rt)
        #pragma unroll
        for (int ct = 0; ct < 2; ++ct) {
            const int n = n0 + wc + ct*16 + l;
            const float bias = b0p[n];
            #pragma unroll
            for (int r = 0; r < 4; ++r) {
                const int m = m0 + wr + rt*16 + qd*4 + r;
                out[(size_t)m*1024 + n] = acc[rt][ct][r] + bias;
            }
        }
}

// ---------------------------------------------------------------------------
// MFMA flash attention — R14 verbatim: sa2 schedule + XCD-contiguous remap
// (per-XCD 4 bh x 16 q-blocks -> K/V working set 2 MB, L2-resident).
// 8 waves x 16 queries, 3 static K/V buffers, one s_barrier + counted
// vwait<2> per K-tile, stage-ahead-2; swizzled staging/reads; P separate.
__global__ __launch_bounds__(512) void attn_mfma(
    const short* __restrict__ qg, const short* __restrict__ kg,
    const short* __restrict__ vtg, short* __restrict__ og)
{
    __shared__ __align__(16) short K0[64*64];
    __shared__ __align__(16) short K1[64*64];
    __shared__ __align__(16) short K2[64*64];
    __shared__ __align__(16) short V0[64*64];
    __shared__ __align__(16) short V1[64*64];
    __shared__ __align__(16) short V2[64*64];
    __shared__ __align__(16) short Pb[128*64];

    const int t = threadIdx.x;
    const int w = t >> 6;                  // 0..7
    const int lane = t & 63;
    const int qd = lane >> 4, l = lane & 15;
    const int l7 = lane & 7;
    const int bid = blockIdx.x;
    const int xcd = bid & 7, idx = bid >> 3;   // idx 0..63
    const int bh = xcd * 4 + (idx >> 4);       // 0..31
    const int q0 = (idx & 15) * 128;

    const int rl  = lane >> 3;
    const int ss8 = ((lane & 7) ^ rl) << 3;

    short8 qf[2];
    const short* qb = qg + ((size_t)bh*2048 + q0 + w*16)*64;
    #pragma unroll
    for (int kf = 0; kf < 2; ++kf)
        qf[kf] = *(const short8*)&qb[l*64 + kf*32 + qd*8];

    f32x4 oacc[4] = {};
    float lsum = 0.f;

    const short* kbase = kg  + (size_t)bh*2048*64;
    const short* vbase = vtg + (size_t)bh*64*2048;
    const float SC = 0.125f * 1.44269504088896340736f;

    auto PREF = [&](int c, short* Kd, short* Vd) {
        gload_lds16(kbase + (size_t)(c*64 + w*8 + rl)*64 + ss8,   &Kd[(w*8)*64]);
        gload_lds16(vbase + (size_t)(w*8 + rl)*2048 + c*64 + ss8, &Vd[(w*8)*64]);
    };

    auto TILE = [&](const short* Kc, const short* Vc) {
        f32x4 sacc[4] = {};
        #pragma unroll
        for (int ct = 0; ct < 4; ++ct) {
            short8 k0f = *(const short8*)&Kc[(ct*16 + l)*64 + (((0 + qd) ^ l7) << 3)];
            short8 k1f = *(const short8*)&Kc[(ct*16 + l)*64 + (((4 + qd) ^ l7) << 3)];
            sacc[ct] = __builtin_amdgcn_mfma_f32_16x16x32_bf16(k0f, qf[0], sacc[ct], 0, 0, 0);
            sacc[ct] = __builtin_amdgcn_mfma_f32_16x16x32_bf16(k1f, qf[1], sacc[ct], 0, 0, 0);
        }
        #pragma unroll
        for (int ct = 0; ct < 4; ++ct) {
            float p0 = exp2f(sacc[ct][0] * SC);
            float p1 = exp2f(sacc[ct][1] * SC);
            float p2 = exp2f(sacc[ct][2] * SC);
            float p3 = exp2f(sacc[ct][3] * SC);
            lsum += (p0 + p1) + (p2 + p3);
            union { unsigned u[2]; short4v s; } cv;
            asm("v_cvt_pk_bf16_f32 %0, %1, %2" : "=v"(cv.u[0]) : "v"(p0), "v"(p1));
            asm("v_cvt_pk_bf16_f32 %0, %1, %2" : "=v"(cv.u[1]) : "v"(p2), "v"(p3));
            *(short4v*)&Pb[(w*16 + l)*64 + (((ct*32 + qd*8) ^ (l7 << 4)) >> 1)] = cv.s;
        }
        #pragma unroll
        for (int kf = 0; kf < 2; ++kf) {
            const int so = ((kf*4 + qd) ^ l7) << 3;
            short8 pa = *(const short8*)&Pb[(w*16 + l)*64 + so];
            #pragma unroll
            for (int ht = 0; ht < 4; ++ht) {
                short8 vb = *(const short8*)&Vc[(ht*16 + l)*64 + so];
                oacc[ht] = __builtin_amdgcn_mfma_f32_16x16x32_bf16(pa, vb, oacc[ht], 0, 0, 0);
            }
        }
    };

    PREF(0, K0, V0);
    PREF(1, K1, V1);
    for (int p = 0; p <= 27; p += 3) {
        vwait<2>(); bar();
        PREF(p + 2, K2, V2);
        TILE(K0, V0);
        vwait<2>(); bar();
        PREF(p + 3, K0, V0);
        TILE(K1, V1);
        vwait<2>(); bar();
        PREF(p + 4, K1, V1);
        TILE(K2, V2);
    }
    vwait<2>(); bar();
    TILE(K0, V0);
    vwait<0>(); bar();
    TILE(K1, V1);

    lsum += __shfl_xor(lsum, 16);
    lsum += __shfl_xor(lsum, 32);
    float inv[4];
    #pragma unroll
    for (int r = 0; r < 4; ++r)
        inv[r] = 1.0f / __shfl(lsum, qd*4 + r);

    const int bb = bh >> 4, h = bh & 15;
    #pragma unroll
    for (int ht = 0; ht < 4; ++ht)
        #pragma unroll
        for (int r = 0; r < 4; ++r) {
            const int s = q0 + w*16 + qd*4 + r;
            og[((size_t)bb*2048 + s)*1024 + h*64 + ht*16 + l] =
                f2bf(oacc[ht][r] * inv[r]);
        }
}

// ---------------------------------------------------------------------------
extern "C" void kernel_launch(void* const* d_in, const int* in_sizes, int n_in,
                              void* d_out, int out_size, void* d_ws, size_t ws_size,
                              hipStream_t stream)
{
    const float* x  = (const float*)d_in[0];
    const float* fr = (const float*)d_in[1];
    const float* Wq = (const float*)d_in[2];
    const float* bq = (const float*)d_in[3];
    const float* Wk = (const float*)d_in[4];
    const float* bk = (const float*)d_in[5];
    const float* Wv = (const float*)d_in[6];
    const float* bv = (const float*)d_in[7];
    const float* Wo = (const float*)d_in[8];
    const float* bo = (const float*)d_in[9];
    float* out = (float*)d_out;

    short* ws    = (short*)d_ws;
    short* xb    = ws;                  // 4,194,304
    short* Wqkvb = xb    + 4194304;     // 3,145,728
    short* Wob   = Wqkvb + 3145728;     // 1,048,576
    short* qg    = Wob   + 1048576;     // [BH,S,HD]
    short* kg    = qg    + 4194304;     // [BH,S,HD]
    short* vtg   = kg    + 4194304;     // [BH,HD,S]
    short* og    = vtg   + 4194304;     // [B,S,H*HD]

    cast_all_kernel<<<8192, 256, 0, stream>>>(x, Wq, Wk, Wv, Wo, xb, Wqkvb, Wob);
    gemm_qkv256<<<192, 512, 0, stream>>>(xb, Wqkvb, bq, bk, bv, fr, qg, kg, vtg);
    attn_mfma<<<512, 512, 0, stream>>>(qg, kg, vtg, og);
    gemm_proj64<<<1024, 256, 0, stream>>>(og, Wob, bo, out);
}